// Round 4
// baseline (454.583 us; speedup 1.0000x reference)
//
#include <hip/hip_runtime.h>
#include <stdint.h>

#define BS_T   16384
#define XDIM   4096
#define KDIM   512
#define NKEYS  4096
#define KTOP   16

typedef _Float16 half8  __attribute__((ext_vector_type(8)));
typedef float    floatx4 __attribute__((ext_vector_type(4)));

// async global->LDS, 16B per lane; LDS dest is wave-uniform base + lane*16
__device__ static inline void gload_lds16(const void* g, void* l) {
  __builtin_amdgcn_global_load_lds(
      (const __attribute__((address_space(1))) uint32_t*)(uintptr_t)g,
      (__attribute__((address_space(3))) uint32_t*)(uint32_t)(uintptr_t)l,
      16, 0, 0);
}

// ---------------- fp32 -> fp16 convert (vectorized, grid-stride) ----------------
__global__ __launch_bounds__(256) void cvt_f32_f16_v(const float* __restrict__ in,
                                                     _Float16* __restrict__ out, int n8) {
  int stride = gridDim.x * 256;
  for (int i = blockIdx.x * 256 + threadIdx.x; i < n8; i += stride) {
    float4 v0 = ((const float4*)in)[2 * i];
    float4 v1 = ((const float4*)in)[2 * i + 1];
    half8 h = { (_Float16)v0.x, (_Float16)v0.y, (_Float16)v0.z, (_Float16)v0.w,
                (_Float16)v1.x, (_Float16)v1.y, (_Float16)v1.z, (_Float16)v1.w };
    ((half8*)out)[i] = h;
  }
}

// ---------------- NT GEMM: C[M,N] = A[M,K] * B[N,K]^T, fp16 in, BK=64 ----------------
// Wave-tile is always 64x64 (WTM=WTN=4): 32.8 flops/LDS-byte keeps the MFMA pipe
// ahead of the 256 B/cy LDS read port. WAVES and wave-grid (WGM x WGN) vary.
// global_load_lds width-16, linear LDS dest + inverse-swizzled global source,
// XOR-swizzled ds_read_b128 (0 bank conflicts, verified R1).
template<int BM, int BN, int WAVES, int WGN, int MINW, bool EPI_Q>
__global__ __launch_bounds__(WAVES * 64, MINW)
void gemm16(const _Float16* __restrict__ A, const _Float16* __restrict__ B,
            const float* __restrict__ bias, void* __restrict__ outp,
            int M, int N, int K, int nCol) {
  __shared__ __align__(16) _Float16 ldsA[BM * 64];
  __shared__ __align__(16) _Float16 ldsB[BN * 64];

  const int tid = threadIdx.x;
  const int cpx = gridDim.x >> 3;
  const int bid = (blockIdx.x & 7) * cpx + (blockIdx.x >> 3);
  const int rowBase = (bid / nCol) * BM;
  const int colBase = (bid % nCol) * BN;
  const int lane = tid & 63;
  const int wid  = tid >> 6;
  const int wr = (wid / WGN) * 64;
  const int wc = (wid % WGN) * 64;
  const int l15 = lane & 15;
  const int q4  = lane >> 4;

  const int sub   = lane >> 3;          // row within the 8-row group
  const int gslot = (lane & 7) ^ sub;   // pre-swizzled global 16B slot

  // staging: (BM+BN)/8 groups of 8 rows x 128B, split evenly across waves
  constexpr int GROUPS = (BM + BN) / 8;
  constexpr int GPW    = GROUPS / WAVES;

  floatx4 acc[4][4];
  #pragma unroll
  for (int m = 0; m < 4; ++m)
    #pragma unroll
    for (int n = 0; n < 4; ++n)
      acc[m][n] = (floatx4)0.0f;

  for (int kt = 0; kt < K; kt += 64) {
    #pragma unroll
    for (int i = 0; i < GPW; ++i) {
      int g = wid * GPW + i;
      if (g < BM / 8) {
        const _Float16* src = A + (size_t)(rowBase + g * 8 + sub) * K + kt + gslot * 8;
        gload_lds16(src, (char*)ldsA + g * 1024);
      } else {
        int gb = g - BM / 8;
        const _Float16* src = B + (size_t)(colBase + gb * 8 + sub) * K + kt + gslot * 8;
        gload_lds16(src, (char*)ldsB + gb * 1024);
      }
    }
    __syncthreads();

    #pragma unroll
    for (int ks = 0; ks < 2; ++ks) {
      const int s = ks * 4 + q4;        // 16B slot 0..7 within the 128B row
      half8 a[4], b[4];
      #pragma unroll
      for (int m = 0; m < 4; ++m) {
        int row = wr + m * 16 + l15;
        a[m] = *(const half8*)((const char*)ldsA + row * 128 + ((s * 16) ^ ((row & 7) << 4)));
      }
      #pragma unroll
      for (int n = 0; n < 4; ++n) {
        int row = wc + n * 16 + l15;
        b[n] = *(const half8*)((const char*)ldsB + row * 128 + ((s * 16) ^ ((row & 7) << 4)));
      }
      #pragma unroll
      for (int m = 0; m < 4; ++m)
        #pragma unroll
        for (int n = 0; n < 4; ++n)
          acc[m][n] = __builtin_amdgcn_mfma_f32_16x16x32_f16(a[m], b[n], acc[m][n], 0, 0, 0);
    }
    __syncthreads();
  }

  // epilogue: C/D layout col=lane&15, row=(lane>>4)*4+r
  #pragma unroll
  for (int m = 0; m < 4; ++m) {
    #pragma unroll
    for (int n = 0; n < 4; ++n) {
      int col = colBase + wc + n * 16 + l15;
      #pragma unroll
      for (int r = 0; r < 4; ++r) {
        int row = rowBase + wr + m * 16 + q4 * 4 + r;
        float v = acc[m][n][r];
        if (EPI_Q) {
          v += bias[col];
          ((_Float16*)outp)[(size_t)row * N + col] = (_Float16)v;
        } else {
          ((float*)outp)[(size_t)row * N + col] = v;
        }
      }
    }
  }
}

// ---------------- top-16 + scatter-softmax gates (radix-select) ----------------
__global__ __launch_bounds__(256) void topk_gates_kernel(const float* __restrict__ scores,
                                                         float* __restrict__ gates) {
  __shared__ uint32_t hist[4096];            // 16KB; reused as candidate store
  __shared__ uint32_t sA[256];
  __shared__ uint32_t av[16], ai[16];
  __shared__ uint32_t sk[KTOP], si[KTOP];
  __shared__ uint32_t cntA, cntC;
  __shared__ int s_p; __shared__ uint32_t s_above;
  __shared__ float gk[KTOP]; __shared__ float s_gother;

  const int tid  = threadIdx.x;
  const int lane = tid & 63;
  const int w    = tid >> 6;
  const float* srow = scores + (size_t)blockIdx.x * NKEYS;

  uint4 z4 = {0, 0, 0, 0};
  #pragma unroll
  for (int i = 0; i < 4; ++i) ((uint4*)hist)[tid + 256 * i] = z4;
  if (tid == 0) { cntA = 0; cntC = 0; }

  uint32_t key[16];
  const int base = (w << 10) + (lane << 4);
  {
    const float4* p4 = (const float4*)(srow + base);
    #pragma unroll
    for (int i = 0; i < 4; ++i) {
      float4 t = p4[i];
      float tv[4] = { t.x, t.y, t.z, t.w };
      #pragma unroll
      for (int c = 0; c < 4; ++c) {
        uint32_t u = __float_as_uint(tv[c]);
        key[i * 4 + c] = u ^ (uint32_t)(((int32_t)u >> 31) | 0x80000000);
      }
    }
  }
  __syncthreads();

  #pragma unroll
  for (int j = 0; j < 16; ++j) atomicAdd(&hist[key[j] >> 20], 1u);
  __syncthreads();

  uint32_t h[16];
  #pragma unroll
  for (int i = 0; i < 16; ++i) h[i] = hist[tid * 16 + i];
  uint32_t sfx[17]; sfx[16] = 0;
  #pragma unroll
  for (int i = 15; i >= 0; --i) sfx[i] = sfx[i + 1] + h[i];
  sA[tid] = sfx[0];
  __syncthreads();
  uint32_t s = sfx[0];
  #pragma unroll
  for (int off = 1; off < 256; off <<= 1) {
    uint32_t add = (tid + off < 256) ? sA[tid + off] : 0;
    __syncthreads();
    s += add; sA[tid] = s;
    __syncthreads();
  }
  const uint32_t exclHi = s - sfx[0];

  #pragma unroll
  for (int i = 0; i < 16; ++i) {
    uint32_t cg = exclHi + sfx[i + 1];
    if (cg < KTOP && cg + h[i] >= KTOP) { s_p = tid * 16 + i; s_above = cg; }
  }
  __syncthreads();
  const uint32_t p = (uint32_t)s_p;
  const uint32_t above = s_above;
  const uint32_t need = KTOP - above;

  uint32_t* ck = hist;
  uint32_t* ci = hist + 2048;
  #pragma unroll
  for (int j = 0; j < 16; ++j) {
    uint32_t b = key[j] >> 20;
    if (b >= p) {
      uint32_t idx = (uint32_t)(base + j);
      if (b > p) { uint32_t pos = atomicAdd(&cntA, 1u); av[pos] = key[j]; ai[pos] = idx; }
      else       { uint32_t pos = atomicAdd(&cntC, 1u); if (pos < 2048u) { ck[pos] = key[j]; ci[pos] = idx; } }
    }
  }
  __syncthreads();

  const uint32_t nA = cntA;
  if (tid < nA) { sk[tid] = av[tid]; si[tid] = ai[tid]; }

  if (w == 0) {
    const uint32_t nC = min(cntC, 2048u);
    for (uint32_t k = 0; k < need; ++k) {
      uint32_t bk = 0, bi = 0xFFFFFFFFu, bp = 0;
      for (uint32_t c = lane; c < nC; c += 64) {
        uint32_t kk = ck[c], ii = ci[c];
        if (kk > bk || (kk == bk && ii < bi)) { bk = kk; bi = ii; bp = c; }
      }
      #pragma unroll
      for (int off = 32; off >= 1; off >>= 1) {
        uint32_t ok = __shfl_down(bk, off);
        uint32_t oi = __shfl_down(bi, off);
        uint32_t op = __shfl_down(bp, off);
        if (ok > bk || (ok == bk && oi < bi)) { bk = ok; bi = oi; bp = op; }
      }
      bp = __shfl(bp, 0);
      if (lane == 0) { ck[bp] = 0; sk[nA + k] = bk; si[nA + k] = bi; }
    }
  }
  __syncthreads();

  if (tid == 0) {
    float f[KTOP]; float mx = 0.f;
    #pragma unroll
    for (int k = 0; k < KTOP; ++k) {
      uint32_t kk = sk[k];
      float fv = (kk & 0x80000000u) ? __uint_as_float(kk ^ 0x80000000u)
                                    : __uint_as_float(~kk);
      f[k] = fv; mx = fmaxf(mx, fv);
    }
    float eo = __expf(-mx);
    float Z = (float)(NKEYS - KTOP) * eo;
    float e[KTOP];
    #pragma unroll
    for (int k = 0; k < KTOP; ++k) { e[k] = __expf(f[k] - mx); Z += e[k]; }
    float inv = 1.f / Z;
    #pragma unroll
    for (int k = 0; k < KTOP; ++k) gk[k] = e[k] * inv;
    s_gother = eo * inv;
  }
  __syncthreads();

  float go = s_gother;
  float4 g4 = { go, go, go, go };
  float* grow = gates + (size_t)blockIdx.x * NKEYS;
  #pragma unroll
  for (int j = 0; j < 4; ++j) ((float4*)grow)[j * 256 + tid] = g4;
  __syncthreads();
  if (tid < KTOP) grow[si[tid]] = gk[tid];
}

extern "C" void kernel_launch(void* const* d_in, const int* in_sizes, int n_in,
                              void* d_out, int out_size, void* d_ws, size_t ws_size,
                              hipStream_t stream) {
  const float* x    = (const float*)d_in[0];
  const float* keys = (const float*)d_in[1];
  const float* W    = (const float*)d_in[2];
  const float* bias = (const float*)d_in[3];
  (void)in_sizes; (void)n_in; (void)out_size; (void)ws_size;

  float* gates  = (float*)d_out;
  float* scores = (float*)d_out + (size_t)BS_T * NKEYS;

  _Float16* W_h = (_Float16*)d_ws;                 // 4 MB
  _Float16* k_h = W_h + (size_t)KDIM * XDIM;       // 4 MB
  _Float16* q_h = k_h + (size_t)NKEYS * KDIM;      // 16 MB
  // x_h (128 MB fp16) lives in the gates half of d_out; topk rewrites gates last
  _Float16* x_h = (_Float16*)gates;

  cvt_f32_f16_v<<<dim3(4096), dim3(256), 0, stream>>>(x, x_h, BS_T * XDIM / 8);
  cvt_f32_f16_v<<<dim3(1024), dim3(256), 0, stream>>>(W, W_h, KDIM * XDIM / 8);
  cvt_f32_f16_v<<<dim3(1024), dim3(256), 0, stream>>>(keys, k_h, NKEYS * KDIM / 8);

  // query = x @ W^T + b -> q_h (fp16). 128x64 tiles, 2 waves (64x64 wave-tile),
  // grid 1024, LDS 24KB -> 4 blocks/CU
  gemm16<128, 64, 2, 1, 2, true><<<dim3((BS_T / 128) * (KDIM / 64)), dim3(128), 0, stream>>>(
      x_h, W_h, bias, q_h, BS_T, KDIM, XDIM, KDIM / 64);

  // scores = q @ keys^T -> fp32. 128x128 tiles, 4 waves (2x2), grid 4096
  gemm16<128, 128, 4, 2, 3, false><<<dim3((BS_T / 128) * (NKEYS / 128)), dim3(256), 0, stream>>>(
      q_h, k_h, nullptr, scores, BS_T, NKEYS, KDIM, NKEYS / 128);

  topk_gates_kernel<<<dim3(BS_T), dim3(256), 0, stream>>>(scores, gates);
}

// Round 5
// 381.145 us; speedup vs baseline: 1.1927x; 1.1927x over previous
//
#include <hip/hip_runtime.h>
#include <stdint.h>

#define BS_T   16384
#define XDIM   4096
#define KDIM   512
#define NKEYS  4096
#define KTOP   16

typedef _Float16 half8  __attribute__((ext_vector_type(8)));
typedef float    floatx4 __attribute__((ext_vector_type(4)));

// async global->LDS, 16B per lane; LDS dest is wave-uniform base + lane*16
__device__ static inline void gload_lds16(const void* g, void* l) {
  __builtin_amdgcn_global_load_lds(
      (const __attribute__((address_space(1))) uint32_t*)(uintptr_t)g,
      (__attribute__((address_space(3))) uint32_t*)(uint32_t)(uintptr_t)l,
      16, 0, 0);
}

// ---------------- fp32 -> fp16 convert (vectorized, grid-stride) ----------------
__global__ __launch_bounds__(256) void cvt_f32_f16_v(const float* __restrict__ in,
                                                     _Float16* __restrict__ out, int n8) {
  int stride = gridDim.x * 256;
  for (int i = blockIdx.x * 256 + threadIdx.x; i < n8; i += stride) {
    float4 v0 = ((const float4*)in)[2 * i];
    float4 v1 = ((const float4*)in)[2 * i + 1];
    half8 h = { (_Float16)v0.x, (_Float16)v0.y, (_Float16)v0.z, (_Float16)v0.w,
                (_Float16)v1.x, (_Float16)v1.y, (_Float16)v1.z, (_Float16)v1.w };
    ((half8*)out)[i] = h;
  }
}

// ---------------- GEMM1 fused: Q[M,512] = cvt16(X[M,4096]) @ W16[512,4096]^T + b ----
// BM=64, BN=512 (full N): each block reads its X panel exactly ONCE (fp32, converted
// in-register while staging). W16 (4 MB) is L2-resident. 8 waves, 64x64 wave-tile,
// double-buffered LDS (144 KB), 2-phase loop: prefetch(t+1) || compute(t).
__global__ __launch_bounds__(512, 2)
void gemm1_fused(const float* __restrict__ X, const _Float16* __restrict__ Wh,
                 const float* __restrict__ bias, _Float16* __restrict__ Q) {
  __shared__ __align__(16) _Float16 ldsA[2][64 * 64];    // 16 KB
  __shared__ __align__(16) _Float16 ldsB[2][512 * 64];   // 128 KB

  const int tid  = threadIdx.x;
  const int lane = tid & 63;
  const int wid  = tid >> 6;            // 0..7
  const int rowBase = blockIdx.x * 64;
  const int wc  = wid * 64;             // wave's 64-col slice of N
  const int l15 = lane & 15;
  const int q4  = lane >> 4;
  const int sub   = lane >> 3;
  const int gslot = (lane & 7) ^ sub;   // pre-swizzled global slot for gload_lds

  // A staging map: thread -> (row, 16B slot); write swizzled, read swizzled
  const int arow  = tid >> 3;           // 0..63
  const int aslot = tid & 7;
  const float* aSrc = X + (size_t)(rowBase + arow) * XDIM + aslot * 8;
  char* aDst[2];
  aDst[0] = (char*)&ldsA[0][0] + arow * 128 + ((aslot * 16) ^ ((arow & 7) << 4));
  aDst[1] = (char*)&ldsA[1][0] + arow * 128 + ((aslot * 16) ^ ((arow & 7) << 4));

  floatx4 acc[4][4];
  #pragma unroll
  for (int m = 0; m < 4; ++m)
    #pragma unroll
    for (int n = 0; n < 4; ++n)
      acc[m][n] = (floatx4)0.0f;

  auto stageB = [&](int kt, int buf) {
    #pragma unroll
    for (int i = 0; i < 8; ++i) {
      int g = wid * 8 + i;              // 64 groups of 8 rows x 128B
      gload_lds16(Wh + (size_t)(g * 8 + sub) * XDIM + kt + gslot * 8,
                  (char*)&ldsB[buf][0] + g * 1024);
    }
  };
  auto writeA = [&](float4 v0, float4 v1, int buf) {
    half8 h = { (_Float16)v0.x, (_Float16)v0.y, (_Float16)v0.z, (_Float16)v0.w,
                (_Float16)v1.x, (_Float16)v1.y, (_Float16)v1.z, (_Float16)v1.w };
    *(half8*)aDst[buf] = h;
  };
  auto compute = [&](int buf) {
    const char* bA = (const char*)&ldsA[buf][0];
    const char* bB = (const char*)&ldsB[buf][0];
    #pragma unroll
    for (int ks = 0; ks < 2; ++ks) {
      const int s = ks * 4 + q4;
      half8 a[4], b[4];
      #pragma unroll
      for (int m = 0; m < 4; ++m) {
        int row = m * 16 + l15;
        a[m] = *(const half8*)(bA + row * 128 + ((s * 16) ^ ((row & 7) << 4)));
      }
      #pragma unroll
      for (int n = 0; n < 4; ++n) {
        int row = wc + n * 16 + l15;
        b[n] = *(const half8*)(bB + row * 128 + ((s * 16) ^ ((row & 7) << 4)));
      }
      #pragma unroll
      for (int m = 0; m < 4; ++m)
        #pragma unroll
        for (int n = 0; n < 4; ++n)
          acc[m][n] = __builtin_amdgcn_mfma_f32_16x16x32_f16(a[m], b[n], acc[m][n], 0, 0, 0);
    }
  };

  // prologue: stage tile 0 into buf 0
  {
    float4 v0 = *(const float4*)(aSrc + 0);
    float4 v1 = *(const float4*)(aSrc + 4);
    stageB(0, 0);
    writeA(v0, v1, 0);
  }
  __syncthreads();

  int cur = 0;
  #pragma unroll 2
  for (int t = 0; t < 63; ++t) {
    const int ktn = (t + 1) * 64;
    float4 v0 = *(const float4*)(aSrc + ktn);       // prefetch A (fp32) to regs
    float4 v1 = *(const float4*)(aSrc + ktn + 4);
    stageB(ktn, cur ^ 1);                           // prefetch B -> LDS (async)
    compute(cur);                                   // MFMA on current tile
    writeA(v0, v1, cur ^ 1);                        // cvt + ds_write (waits A regs)
    __syncthreads();                                // drains vmcnt (B) + lgkm (A writes)
    cur ^= 1;
  }
  compute(cur);

  // epilogue: C/D layout col=lane&15, row=(lane>>4)*4+r; fused bias + fp16 store
  #pragma unroll
  for (int m = 0; m < 4; ++m) {
    #pragma unroll
    for (int n = 0; n < 4; ++n) {
      int col = wc + n * 16 + l15;
      float bv = bias[col];
      #pragma unroll
      for (int r = 0; r < 4; ++r) {
        int row = rowBase + m * 16 + q4 * 4 + r;
        Q[(size_t)row * KDIM + col] = (_Float16)(acc[m][n][r] + bv);
      }
    }
  }
}

// ---------------- NT GEMM2: C[M,N] = A[M,K] * B[N,K]^T, fp16 in, fp32 out ----------
template<int BM, int BN, int WAVES, int WGN, int MINW>
__global__ __launch_bounds__(WAVES * 64, MINW)
void gemm16(const _Float16* __restrict__ A, const _Float16* __restrict__ B,
            float* __restrict__ outp, int M, int N, int K, int nCol) {
  __shared__ __align__(16) _Float16 ldsA[BM * 64];
  __shared__ __align__(16) _Float16 ldsB[BN * 64];

  const int tid = threadIdx.x;
  const int cpx = gridDim.x >> 3;
  const int bid = (blockIdx.x & 7) * cpx + (blockIdx.x >> 3);
  const int rowBase = (bid / nCol) * BM;
  const int colBase = (bid % nCol) * BN;
  const int lane = tid & 63;
  const int wid  = tid >> 6;
  const int wr = (wid / WGN) * 64;
  const int wc = (wid % WGN) * 64;
  const int l15 = lane & 15;
  const int q4  = lane >> 4;

  const int sub   = lane >> 3;
  const int gslot = (lane & 7) ^ sub;

  constexpr int GROUPS = (BM + BN) / 8;
  constexpr int GPW    = GROUPS / WAVES;

  floatx4 acc[4][4];
  #pragma unroll
  for (int m = 0; m < 4; ++m)
    #pragma unroll
    for (int n = 0; n < 4; ++n)
      acc[m][n] = (floatx4)0.0f;

  for (int kt = 0; kt < K; kt += 64) {
    #pragma unroll
    for (int i = 0; i < GPW; ++i) {
      int g = wid * GPW + i;
      if (g < BM / 8) {
        const _Float16* src = A + (size_t)(rowBase + g * 8 + sub) * K + kt + gslot * 8;
        gload_lds16(src, (char*)ldsA + g * 1024);
      } else {
        int gb = g - BM / 8;
        const _Float16* src = B + (size_t)(colBase + gb * 8 + sub) * K + kt + gslot * 8;
        gload_lds16(src, (char*)ldsB + gb * 1024);
      }
    }
    __syncthreads();

    #pragma unroll
    for (int ks = 0; ks < 2; ++ks) {
      const int s = ks * 4 + q4;
      half8 a[4], b[4];
      #pragma unroll
      for (int m = 0; m < 4; ++m) {
        int row = wr + m * 16 + l15;
        a[m] = *(const half8*)((const char*)ldsA + row * 128 + ((s * 16) ^ ((row & 7) << 4)));
      }
      #pragma unroll
      for (int n = 0; n < 4; ++n) {
        int row = wc + n * 16 + l15;
        b[n] = *(const half8*)((const char*)ldsB + row * 128 + ((s * 16) ^ ((row & 7) << 4)));
      }
      #pragma unroll
      for (int m = 0; m < 4; ++m)
        #pragma unroll
        for (int n = 0; n < 4; ++n)
          acc[m][n] = __builtin_amdgcn_mfma_f32_16x16x32_f16(a[m], b[n], acc[m][n], 0, 0, 0);
    }
    __syncthreads();
  }

  #pragma unroll
  for (int m = 0; m < 4; ++m) {
    #pragma unroll
    for (int n = 0; n < 4; ++n) {
      int col = colBase + wc + n * 16 + l15;
      #pragma unroll
      for (int r = 0; r < 4; ++r) {
        int row = rowBase + wr + m * 16 + q4 * 4 + r;
        outp[(size_t)row * N + col] = acc[m][n][r];
      }
    }
  }
}

// ---------------- top-16 + scatter-softmax gates (radix-select) ----------------
__global__ __launch_bounds__(256) void topk_gates_kernel(const float* __restrict__ scores,
                                                         float* __restrict__ gates) {
  __shared__ uint32_t hist[4096];            // 16KB; reused as candidate store
  __shared__ uint32_t sA[256];
  __shared__ uint32_t av[16], ai[16];
  __shared__ uint32_t sk[KTOP], si[KTOP];
  __shared__ uint32_t cntA, cntC;
  __shared__ int s_p; __shared__ uint32_t s_above;
  __shared__ float gk[KTOP]; __shared__ float s_gother;

  const int tid  = threadIdx.x;
  const int lane = tid & 63;
  const int w    = tid >> 6;
  const float* srow = scores + (size_t)blockIdx.x * NKEYS;

  uint4 z4 = {0, 0, 0, 0};
  #pragma unroll
  for (int i = 0; i < 4; ++i) ((uint4*)hist)[tid + 256 * i] = z4;
  if (tid == 0) { cntA = 0; cntC = 0; }

  uint32_t key[16];
  const int base = (w << 10) + (lane << 4);
  {
    const float4* p4 = (const float4*)(srow + base);
    #pragma unroll
    for (int i = 0; i < 4; ++i) {
      float4 t = p4[i];
      float tv[4] = { t.x, t.y, t.z, t.w };
      #pragma unroll
      for (int c = 0; c < 4; ++c) {
        uint32_t u = __float_as_uint(tv[c]);
        key[i * 4 + c] = u ^ (uint32_t)(((int32_t)u >> 31) | 0x80000000);
      }
    }
  }
  __syncthreads();

  #pragma unroll
  for (int j = 0; j < 16; ++j) atomicAdd(&hist[key[j] >> 20], 1u);
  __syncthreads();

  uint32_t h[16];
  #pragma unroll
  for (int i = 0; i < 16; ++i) h[i] = hist[tid * 16 + i];
  uint32_t sfx[17]; sfx[16] = 0;
  #pragma unroll
  for (int i = 15; i >= 0; --i) sfx[i] = sfx[i + 1] + h[i];
  sA[tid] = sfx[0];
  __syncthreads();
  uint32_t s = sfx[0];
  #pragma unroll
  for (int off = 1; off < 256; off <<= 1) {
    uint32_t add = (tid + off < 256) ? sA[tid + off] : 0;
    __syncthreads();
    s += add; sA[tid] = s;
    __syncthreads();
  }
  const uint32_t exclHi = s - sfx[0];

  #pragma unroll
  for (int i = 0; i < 16; ++i) {
    uint32_t cg = exclHi + sfx[i + 1];
    if (cg < KTOP && cg + h[i] >= KTOP) { s_p = tid * 16 + i; s_above = cg; }
  }
  __syncthreads();
  const uint32_t p = (uint32_t)s_p;
  const uint32_t above = s_above;
  const uint32_t need = KTOP - above;

  uint32_t* ck = hist;
  uint32_t* ci = hist + 2048;
  #pragma unroll
  for (int j = 0; j < 16; ++j) {
    uint32_t b = key[j] >> 20;
    if (b >= p) {
      uint32_t idx = (uint32_t)(base + j);
      if (b > p) { uint32_t pos = atomicAdd(&cntA, 1u); av[pos] = key[j]; ai[pos] = idx; }
      else       { uint32_t pos = atomicAdd(&cntC, 1u); if (pos < 2048u) { ck[pos] = key[j]; ci[pos] = idx; } }
    }
  }
  __syncthreads();

  const uint32_t nA = cntA;
  if (tid < nA) { sk[tid] = av[tid]; si[tid] = ai[tid]; }

  if (w == 0) {
    const uint32_t nC = min(cntC, 2048u);
    for (uint32_t k = 0; k < need; ++k) {
      uint32_t bk = 0, bi = 0xFFFFFFFFu, bp = 0;
      for (uint32_t c = lane; c < nC; c += 64) {
        uint32_t kk = ck[c], ii = ci[c];
        if (kk > bk || (kk == bk && ii < bi)) { bk = kk; bi = ii; bp = c; }
      }
      #pragma unroll
      for (int off = 32; off >= 1; off >>= 1) {
        uint32_t ok = __shfl_down(bk, off);
        uint32_t oi = __shfl_down(bi, off);
        uint32_t op = __shfl_down(bp, off);
        if (ok > bk || (ok == bk && oi < bi)) { bk = ok; bi = oi; bp = op; }
      }
      bp = __shfl(bp, 0);
      if (lane == 0) { ck[bp] = 0; sk[nA + k] = bk; si[nA + k] = bi; }
    }
  }
  __syncthreads();

  if (tid == 0) {
    float f[KTOP]; float mx = 0.f;
    #pragma unroll
    for (int k = 0; k < KTOP; ++k) {
      uint32_t kk = sk[k];
      float fv = (kk & 0x80000000u) ? __uint_as_float(kk ^ 0x80000000u)
                                    : __uint_as_float(~kk);
      f[k] = fv; mx = fmaxf(mx, fv);
    }
    float eo = __expf(-mx);
    float Z = (float)(NKEYS - KTOP) * eo;
    float e[KTOP];
    #pragma unroll
    for (int k = 0; k < KTOP; ++k) { e[k] = __expf(f[k] - mx); Z += e[k]; }
    float inv = 1.f / Z;
    #pragma unroll
    for (int k = 0; k < KTOP; ++k) gk[k] = e[k] * inv;
    s_gother = eo * inv;
  }
  __syncthreads();

  float go = s_gother;
  float4 g4 = { go, go, go, go };
  float* grow = gates + (size_t)blockIdx.x * NKEYS;
  #pragma unroll
  for (int j = 0; j < 4; ++j) ((float4*)grow)[j * 256 + tid] = g4;
  __syncthreads();
  if (tid < KTOP) grow[si[tid]] = gk[tid];
}

extern "C" void kernel_launch(void* const* d_in, const int* in_sizes, int n_in,
                              void* d_out, int out_size, void* d_ws, size_t ws_size,
                              hipStream_t stream) {
  const float* x    = (const float*)d_in[0];
  const float* keys = (const float*)d_in[1];
  const float* W    = (const float*)d_in[2];
  const float* bias = (const float*)d_in[3];
  (void)in_sizes; (void)n_in; (void)out_size; (void)ws_size;

  float* gates  = (float*)d_out;
  float* scores = (float*)d_out + (size_t)BS_T * NKEYS;

  _Float16* W_h = (_Float16*)d_ws;                 // 4 MB
  _Float16* k_h = W_h + (size_t)KDIM * XDIM;       // 4 MB
  _Float16* q_h = k_h + (size_t)NKEYS * KDIM;      // 16 MB

  cvt_f32_f16_v<<<dim3(1024), dim3(256), 0, stream>>>(W, W_h, KDIM * XDIM / 8);
  cvt_f32_f16_v<<<dim3(1024), dim3(256), 0, stream>>>(keys, k_h, NKEYS * KDIM / 8);

  // query = x @ W^T + b -> q_h (fp16); x read ONCE (fp32), converted in-register
  gemm1_fused<<<dim3(BS_T / 64), dim3(512), 0, stream>>>(x, W_h, bias, q_h);

  // scores = q @ keys^T -> fp32. 128x128 tiles, 4 waves (2x2), grid 4096
  gemm16<128, 128, 4, 2, 3><<<dim3((BS_T / 128) * (NKEYS / 128)), dim3(256), 0, stream>>>(
      q_h, k_h, scores, BS_T, NKEYS, KDIM, NKEYS / 128);

  topk_gates_kernel<<<dim3(BS_T), dim3(256), 0, stream>>>(scores, gates);
}